// Round 8
// baseline (100.728 us; speedup 1.0000x reference)
//
#include <hip/hip_runtime.h>
#include <stdint.h>

// QuantLinear eval forward — v8: plain stores + 2 wave generations.
// B=524288 rows, IN_DIM=16 (64B/row), OUT_DIM=32 (128B/row), 4 chunks of 4.
// vs v7: (a) removed non-temporal store hint (L2 write-combining path, like
// the 6.4 TB/s fill kernels); (b) 4096 blocks x 32 rows/wave -> 16384 waves
// = 2 generations per CU slot, so fresh waves issue loads while older waves
// compute (kills whole-chip load-phase convoying); (c) dot fallback chain
// udot4 -> sad_u8 -> mul so the byte-sum is full-rate everywhere.
// Integer math path identical to r1-r7 (absmax 0).

#if __has_builtin(__builtin_amdgcn_udot4)
#define DOT_TIER 2
#elif __has_builtin(__builtin_amdgcn_sad_u8)
#define DOT_TIER 1
#else
#define DOT_TIER 0
#endif

typedef float f32x4 __attribute__((ext_vector_type(4)));

// floor(x/15) for x in [0,127] — full-rate 24-bit multiply, exact.
__device__ __forceinline__ int rnd15(int x) {
    return (int)(__umul24((unsigned)x, 274u) >> 12);
}

#if DOT_TIER == 2
// masks have bytes {0,1}; one full-rate dot per sum, +7 folded into init
#define TERM(q, mp, mm)                                                     \
    (rnd15((int)__builtin_amdgcn_udot4((q), (mp), 7u, false)) -             \
     rnd15((int)__builtin_amdgcn_udot4((q), (mm), 7u, false)))
#elif DOT_TIER == 1
// masks have bytes {0,0xFF}; v_sad_u8(x,0,acc) = byte-sum of x + acc, full-rate
#define TERM(q, mp, mm)                                                     \
    (rnd15((int)__builtin_amdgcn_sad_u8((q) & (mp), 0u, 7u)) -              \
     rnd15((int)__builtin_amdgcn_sad_u8((q) & (mm), 0u, 7u)))
#else
#define BSUM(x) ((int)((uint32_t)((x) * 0x01010101u) >> 24))
#define TERM(q, mp, mm)                                                     \
    (rnd15(BSUM((q) & (mp)) + 7) - rnd15(BSUM((q) & (mm)) + 7))
#endif

__global__ __launch_bounds__(256) void qlin_main(
    const float* __restrict__ in, const float* __restrict__ wgt,
    const float* __restrict__ pmin, const float* __restrict__ pmax,
    float* __restrict__ out, int nrows)
{
    __shared__ __align__(16) uint32_t cmP[128];     // [o*4+c] P-mask
    __shared__ __align__(16) uint32_t cmM[128];     // [o*4+c] M-mask
    __shared__ __align__(16) float sbias[32];
    __shared__ __align__(16) uint32_t xpose[256];   // 64 words per wave

    const int t = threadIdx.x;
    const int lane = t & 63;
    const int wv = t >> 6;
    const size_t R0 = ((size_t)blockIdx.x * 4 + wv) * 32;   // 32 rows per wave
    (void)nrows;   // grid covers rows exactly

    // issue both slab loads now; mask build + barrier hide the latency
    const float4* inp = (const float4*)in + R0 * 4 + lane;
    float4 f0 = inp[0], f1 = inp[64];

    const uint32_t MB = (DOT_TIER == 2) ? 1u : 0xFFu;

    // --- build P/M masks (128 words each) ---
    if (t < 128) {
        const int o = t >> 2, c = t & 3;
        const float* wrow = wgt + o * 16 + c * 4;
        uint32_t mp = 0, mm = 0;
#pragma unroll
        for (int j = 0; j < 4; ++j) {
            float v = wrow[j];
            if (v > 0.0f) mp |= MB << (8 * j);
            if (v < 0.0f) mm |= MB << (8 * j);
        }
        cmP[t] = mp;
        cmM[t] = mm;
    }
    // --- bias[o] = InMin * sum_j sign(w[o,j]) ---
    if (t < 32) {
        const float* wrow = wgt + t * 16;
        int s = 0;
#pragma unroll
        for (int j = 0; j < 16; ++j) {
            float v = wrow[j];
            s += (v > 0.0f) ? 1 : 0;
            s -= (v < 0.0f) ? 1 : 0;
        }
        sbias[t] = __fmul_rn(pmin[0], (float)s);
    }
    __syncthreads();

    const int ogrp = lane & 7;        // 4-output group this lane owns
    const int rsel = lane >> 3;       // row-within-8 this lane owns
    uint32_t* xp = xpose + (wv << 6);

    // hoist this lane's 4x4 P/M mask words into registers
    const uint4 P0 = *(const uint4*)&cmP[(ogrp * 4 + 0) * 4];
    const uint4 P1 = *(const uint4*)&cmP[(ogrp * 4 + 1) * 4];
    const uint4 P2 = *(const uint4*)&cmP[(ogrp * 4 + 2) * 4];
    const uint4 P3 = *(const uint4*)&cmP[(ogrp * 4 + 3) * 4];
    const uint4 M0 = *(const uint4*)&cmM[(ogrp * 4 + 0) * 4];
    const uint4 M1 = *(const uint4*)&cmM[(ogrp * 4 + 1) * 4];
    const uint4 M2 = *(const uint4*)&cmM[(ogrp * 4 + 2) * 4];
    const uint4 M3 = *(const uint4*)&cmM[(ogrp * 4 + 3) * 4];
    const float4 bias = *(const float4*)(sbias + ogrp * 4);

    const float InMin = pmin[0];
    const float scale = __fsub_rn(pmax[0], InMin);
    // scalarize the unit-scale test -> only the taken quantize path executes
    const bool unit =
        (__builtin_amdgcn_readfirstlane(__float_as_uint(scale)) == 0x3f800000u);

#define QUANT1(EJ, PK, J)                                                   \
        {                                                                   \
            float v  = __fmul_rn(EJ, 15.0f);                                \
            float rr = rintf(v);                                            \
            rr = fminf(fmaxf(rr, 0.0f), 15.0f);                             \
            PK |= ((uint32_t)(int)rr) << (8 * (J));                         \
        }

#define QUANT(F, QW)                                                        \
    {                                                                       \
        uint32_t pk = 0;                                                    \
        if (unit) {                                                         \
            QUANT1(__fsub_rn(F.x, InMin), pk, 0)                            \
            QUANT1(__fsub_rn(F.y, InMin), pk, 1)                            \
            QUANT1(__fsub_rn(F.z, InMin), pk, 2)                            \
            QUANT1(__fsub_rn(F.w, InMin), pk, 3)                            \
        } else {                                                            \
            QUANT1(__fdiv_rn(__fsub_rn(F.x, InMin), scale), pk, 0)          \
            QUANT1(__fdiv_rn(__fsub_rn(F.y, InMin), scale), pk, 1)          \
            QUANT1(__fdiv_rn(__fsub_rn(F.z, InMin), scale), pk, 2)          \
            QUANT1(__fdiv_rn(__fsub_rn(F.w, InMin), scale), pk, 3)          \
        }                                                                   \
        QW = pk;                                                            \
    }

#define ROWCOMP(q0, q1, q2, q3, dst)                                        \
        {                                                                   \
            int a0 = TERM(q0, P0.x, M0.x) + TERM(q1, P0.y, M0.y)            \
                   + TERM(q2, P0.z, M0.z) + TERM(q3, P0.w, M0.w);           \
            int a1 = TERM(q0, P1.x, M1.x) + TERM(q1, P1.y, M1.y)            \
                   + TERM(q2, P1.z, M1.z) + TERM(q3, P1.w, M1.w);           \
            int a2 = TERM(q0, P2.x, M2.x) + TERM(q1, P2.y, M2.y)            \
                   + TERM(q2, P2.z, M2.z) + TERM(q3, P2.w, M2.w);           \
            int a3 = TERM(q0, P3.x, M3.x) + TERM(q1, P3.y, M3.y)            \
                   + TERM(q2, P3.z, M3.z) + TERM(q3, P3.w, M3.w);           \
            f32x4 res;                                                      \
            res.x = __fadd_rn(__fmul_rn((float)a0, scale), bias.x);         \
            res.y = __fadd_rn(__fmul_rn((float)a1, scale), bias.y);         \
            res.z = __fadd_rn(__fmul_rn((float)a2, scale), bias.z);         \
            res.w = __fadd_rn(__fmul_rn((float)a3, scale), bias.w);         \
            *(f32x4*)(dst) = res;                                           \
        }

    // Per slab: quantize -> wave-private LDS transpose (same-wave lgkm
    // ordering, no barrier) -> full-rate dot/round -> contiguous 1KB stores.
#define SLAB(F, K)                                                          \
    {                                                                       \
        uint32_t qw;                                                        \
        QUANT(F, qw);                                                       \
        xp[lane] = qw;                                                      \
        const uint4 qA = *(const uint4*)(xp + (rsel << 2));                 \
        const uint4 qB = *(const uint4*)(xp + 32 + (rsel << 2));            \
        float* p0 = out + (R0 + (size_t)(K) * 16 + rsel) * 32 + (ogrp << 2);\
        ROWCOMP(qA.x, qA.y, qA.z, qA.w, p0);                                \
        ROWCOMP(qB.x, qB.y, qB.z, qB.w, p0 + 256);                          \
    }

    SLAB(f0, 0)
    SLAB(f1, 1)

#undef SLAB
#undef ROWCOMP
#undef QUANT
#undef QUANT1
}

extern "C" void kernel_launch(void* const* d_in, const int* in_sizes, int n_in,
                              void* d_out, int out_size, void* d_ws, size_t ws_size,
                              hipStream_t stream) {
    (void)n_in; (void)d_ws; (void)ws_size; (void)out_size;
    const float* in  = (const float*)d_in[0];
    const float* wgt = (const float*)d_in[1];
    const float* mn  = (const float*)d_in[2];
    const float* mx  = (const float*)d_in[3];
    float* out = (float*)d_out;
    const int nrows = in_sizes[0] / 16;        // 524288
    const int blocks = nrows / 128;            // 4096 blocks x 4 waves x 32 rows
    qlin_main<<<blocks, 256, 0, stream>>>(in, wgt, mn, mx, out, nrows);
}

// Round 10
// 97.354 us; speedup vs baseline: 1.0347x; 1.0347x over previous
//
#include <hip/hip_runtime.h>
#include <stdint.h>

// QuantLinear eval forward — v9 (resubmit; r9 was a broker timeout, no data).
// B=524288 rows, IN_DIM=16 (64B/row), OUT_DIM=32 (128B/row), 4 chunks of 4.
// Key algebra: quantized bytes stored as 2q (<=30); P/M mask bytes = 137;
// udot4(q2, m137, 1918) = 274*(y+7), and round(y/15) = that >> 12 (exact for
// y in [0,60], no ties — same integer as r1-r8's verified path). TERM = 5
// full-rate ops (2 dot, 2 shr, 1 sub). Masks+bias built per-wave in
// wave-private LDS (no __syncthreads). Memory skeleton proven r2-r8: 4x1KB
// coalesced wave preloads, wave-private LDS transpose, contiguous 1KB stores.

#if __has_builtin(__builtin_amdgcn_udot4)
#define HAVE_UDOT4 1
#else
#define HAVE_UDOT4 0
#endif

typedef float f32x4 __attribute__((ext_vector_type(4)));

#if HAVE_UDOT4
// q2 bytes = 2q, mask bytes = 137, init 1918 -> 274*(y+7); >>12 = round(y/15)
#define TERM(q2, mp, mm)                                                    \
    ((int)(__builtin_amdgcn_udot4((q2), (mp), 1918u, false) >> 12) -        \
     (int)(__builtin_amdgcn_udot4((q2), (mm), 1918u, false) >> 12))
#define MBYTE 137u
#define QSH 1            // store 2q
#define BPB 3            // popc bits per set mask byte
#else
// fallback: q bytes = q, mask bytes = 0xFF; byte-sum via multiply + umul24 round
#define BSUM(x) ((int)((uint32_t)((x) * 0x01010101u) >> 24))
__device__ __forceinline__ int rnd15f(int x) {
    return (int)(__umul24((unsigned)x, 274u) >> 12);
}
#define TERM(q, mp, mm)                                                     \
    (rnd15f(BSUM((q) & (mp)) + 7) - rnd15f(BSUM((q) & (mm)) + 7))
#define MBYTE 0xFFu
#define QSH 0
#define BPB 8
#endif

__global__ __launch_bounds__(256) void qlin_main(
    const float* __restrict__ in, const float* __restrict__ wgt,
    const float* __restrict__ pmin, const float* __restrict__ pmax,
    float* __restrict__ out, int nrows)
{
    // per-wave private LDS: 128 P + 128 M mask words, 32 bias, 64 xpose
    __shared__ __align__(16) uint32_t sP[4][128];
    __shared__ __align__(16) uint32_t sM[4][128];
    __shared__ __align__(16) float    sB[4][32];
    __shared__ __align__(16) uint32_t sX[4][64];

    const int t = threadIdx.x;
    const int lane = t & 63;
    const int wv = t >> 6;
    const size_t R0 = ((size_t)blockIdx.x * 4 + wv) * 64;   // 64 rows per wave
    (void)nrows;   // grid covers rows exactly

    // issue all 4 slab loads NOW; per-wave prologue hides the latency
    const float4* inp = (const float4*)in + R0 * 4 + lane;
    float4 f0 = inp[0], f1 = inp[64], f2 = inp[128], f3 = inp[192];

    // --- per-wave mask build: lane builds words 2*lane, 2*lane+1 (no barrier,
    //     wave-internal DS ordering suffices) ---
#pragma unroll
    for (int k = 0; k < 2; ++k) {
        const int w = lane * 2 + k;            // w = o*4+c
        const float4 wf = *(const float4*)(wgt + w * 4);
        uint32_t mp = 0, mm = 0;
        const float e[4] = { wf.x, wf.y, wf.z, wf.w };
#pragma unroll
        for (int j = 0; j < 4; ++j) {
            if (e[j] > 0.0f) mp |= MBYTE << (8 * j);
            if (e[j] < 0.0f) mm |= MBYTE << (8 * j);
        }
        sP[wv][w] = mp;
        sM[wv][w] = mm;
    }
    // --- per-wave bias: lane o<32 from mask popcounts (exact: popc%BPB==0) ---
    if (lane < 32) {
        int pc = 0;
#pragma unroll
        for (int c = 0; c < 4; ++c)
            pc += __popc(sP[wv][lane * 4 + c]) - __popc(sM[wv][lane * 4 + c]);
        sB[wv][lane] = __fmul_rn(pmin[0], (float)(pc / BPB));
    }

    const int ogrp = lane & 7;        // 4-output group this lane owns
    const int rsel = lane >> 3;       // row-within-8 this lane owns
    uint32_t* xp = sX[wv];

    // hoist this lane's 4x4 P/M mask words into registers
    const uint4 P0 = *(const uint4*)&sP[wv][(ogrp * 4 + 0) * 4];
    const uint4 P1 = *(const uint4*)&sP[wv][(ogrp * 4 + 1) * 4];
    const uint4 P2 = *(const uint4*)&sP[wv][(ogrp * 4 + 2) * 4];
    const uint4 P3 = *(const uint4*)&sP[wv][(ogrp * 4 + 3) * 4];
    const uint4 M0 = *(const uint4*)&sM[wv][(ogrp * 4 + 0) * 4];
    const uint4 M1 = *(const uint4*)&sM[wv][(ogrp * 4 + 1) * 4];
    const uint4 M2 = *(const uint4*)&sM[wv][(ogrp * 4 + 2) * 4];
    const uint4 M3 = *(const uint4*)&sM[wv][(ogrp * 4 + 3) * 4];
    const float4 bias = *(const float4*)&sB[wv][ogrp * 4];

    const float InMin = pmin[0];
    const float scale = __fsub_rn(pmax[0], InMin);
    // scalarize the unit-scale test -> only the taken quantize path executes
    const bool unit =
        (__builtin_amdgcn_readfirstlane(__float_as_uint(scale)) == 0x3f800000u);

#define QUANT1(EJ, PK, J)                                                   \
        {                                                                   \
            float v  = __fmul_rn(EJ, 15.0f);                                \
            float rr = rintf(v);                                            \
            rr = fminf(fmaxf(rr, 0.0f), 15.0f);                             \
            PK |= ((uint32_t)(int)rr) << (8 * (J) + QSH);                   \
        }

#define QUANT(F, QW)                                                        \
    {                                                                       \
        uint32_t pk = 0;                                                    \
        if (unit) {                                                         \
            QUANT1(__fsub_rn(F.x, InMin), pk, 0)                            \
            QUANT1(__fsub_rn(F.y, InMin), pk, 1)                            \
            QUANT1(__fsub_rn(F.z, InMin), pk, 2)                            \
            QUANT1(__fsub_rn(F.w, InMin), pk, 3)                            \
        } else {                                                            \
            QUANT1(__fdiv_rn(__fsub_rn(F.x, InMin), scale), pk, 0)          \
            QUANT1(__fdiv_rn(__fsub_rn(F.y, InMin), scale), pk, 1)          \
            QUANT1(__fdiv_rn(__fsub_rn(F.z, InMin), scale), pk, 2)          \
            QUANT1(__fdiv_rn(__fsub_rn(F.w, InMin), scale), pk, 3)          \
        }                                                                   \
        QW = pk;                                                            \
    }

#define ROWCOMP(q0, q1, q2, q3, dst)                                        \
        {                                                                   \
            int a0 = TERM(q0, P0.x, M0.x) + TERM(q1, P0.y, M0.y)            \
                   + TERM(q2, P0.z, M0.z) + TERM(q3, P0.w, M0.w);           \
            int a1 = TERM(q0, P1.x, M1.x) + TERM(q1, P1.y, M1.y)            \
                   + TERM(q2, P1.z, M1.z) + TERM(q3, P1.w, M1.w);           \
            int a2 = TERM(q0, P2.x, M2.x) + TERM(q1, P2.y, M2.y)            \
                   + TERM(q2, P2.z, M2.z) + TERM(q3, P2.w, M2.w);           \
            int a3 = TERM(q0, P3.x, M3.x) + TERM(q1, P3.y, M3.y)            \
                   + TERM(q2, P3.z, M3.z) + TERM(q3, P3.w, M3.w);           \
            f32x4 res;                                                      \
            res.x = __fadd_rn(__fmul_rn((float)a0, scale), bias.x);         \
            res.y = __fadd_rn(__fmul_rn((float)a1, scale), bias.y);         \
            res.z = __fadd_rn(__fmul_rn((float)a2, scale), bias.z);         \
            res.w = __fadd_rn(__fmul_rn((float)a3, scale), bias.w);         \
            *(f32x4*)(dst) = res;                                           \
        }

    // Per slab of 16 rows: quantize -> wave-private LDS transpose (same-wave
    // lgkm ordering, no barrier) -> 5-op TERMs -> contiguous 1KB stores.
#define SLAB(F, K)                                                          \
    {                                                                       \
        uint32_t qw;                                                        \
        QUANT(F, qw);                                                       \
        xp[lane] = qw;                                                      \
        const uint4 qA = *(const uint4*)(xp + (rsel << 2));                 \
        const uint4 qB = *(const uint4*)(xp + 32 + (rsel << 2));            \
        float* p0 = out + (R0 + (size_t)(K) * 16 + rsel) * 32 + (ogrp << 2);\
        ROWCOMP(qA.x, qA.y, qA.z, qA.w, p0);                                \
        ROWCOMP(qB.x, qB.y, qB.z, qB.w, p0 + 256);                          \
    }

    SLAB(f0, 0)
    SLAB(f1, 1)
    SLAB(f2, 2)
    SLAB(f3, 3)

#undef SLAB
#undef ROWCOMP
#undef QUANT
#undef QUANT1
}

extern "C" void kernel_launch(void* const* d_in, const int* in_sizes, int n_in,
                              void* d_out, int out_size, void* d_ws, size_t ws_size,
                              hipStream_t stream) {
    (void)n_in; (void)d_ws; (void)ws_size; (void)out_size;
    const float* in  = (const float*)d_in[0];
    const float* wgt = (const float*)d_in[1];
    const float* mn  = (const float*)d_in[2];
    const float* mx  = (const float*)d_in[3];
    float* out = (float*)d_out;
    const int nrows = in_sizes[0] / 16;        // 524288
    const int blocks = nrows / 256;            // 2048 blocks x 4 waves x 64 rows
    qlin_main<<<blocks, 256, 0, stream>>>(in, wgt, mn, mx, out, nrows);
}